// Round 3
// baseline (207.819 us; speedup 1.0000x reference)
//
#include <hip/hip_runtime.h>
#include <hip/hip_bf16.h>

// ---------------------------------------------------------------------------
// BF_NIR_conv, round 3: h1 fully folded into one MFMA chain.
//   U[pos][256] = featc[:,pos] @ W1[0:256,:]   (precomputed bf16, 16384 rows;
//                 rows 16384..16387 = W1[384], W1[385], b1, zeros)
//   Per block (1x16 pixel row, 64 h1-rows = 16 pix x 4 branches):
//     h1^T[n][row] = sum_k A[n][k] * B[k][row]  over K=160:
//       k 0..127   : W1[256+k][n]  x  hr_guide[pix(row)][k]
//       k 128..130 : W1[384]/W1[385]/b1  x  relY/relX/1.0
//       k 131..150 : U[urow(u)][n] x  onehot(row selects u)   <- U gather in-MFMA
//     h1 = relu(.) -> LDS; h2 = relu(h1@W2+b2); pred = h2@W3+b3
//     out = softmax(gc)-weighted sum over branches
// ---------------------------------------------------------------------------

using bf16x8 = __attribute__((ext_vector_type(8))) __bf16;
using f32x4  = __attribute__((ext_vector_type(4))) float;

__device__ __forceinline__ float bf2f(unsigned short u){
  unsigned int x = ((unsigned int)u) << 16;
  return __builtin_bit_cast(float, x);
}
__device__ __forceinline__ unsigned short f2bf(float f){
  unsigned int x = __builtin_bit_cast(unsigned int, f);
  unsigned int r = x + 0x7fffu + ((x >> 16) & 1u);
  return (unsigned short)(r >> 16);
}
__device__ __forceinline__ bf16x8 ld8(const ushort* p){
  uint4 r = *(const uint4*)p;
  return __builtin_bit_cast(bf16x8, r);
}

struct RowMeta { int valid, ix; float relY, relX; int spos; };
__device__ __forceinline__ RowMeta row_meta(int Y, int X, int br){
  int ivx = br >> 1, ivy = br & 1;   // branch: (vx,vy)=(-,-),(-,+),(+,-),(+,+)
  int validY, iy; float relY;
  if (ivx == 0){ validY = (Y >= 1);   iy = (Y-1) >> 1; relY = (Y & 1) ?  0.5f :  1.5f; }
  else         { validY = (Y <= 254); iy = (Y+1) >> 1; relY = (Y & 1) ? -1.5f : -0.5f; }
  int validX, ix; float relX;
  if (ivy == 0){ validX = (X >= 1);   ix = (X-1) >> 1; relX = (X & 1) ?  0.5f :  1.5f; }
  else         { validX = (X <= 254); ix = (X+1) >> 1; relX = (X & 1) ? -1.5f : -0.5f; }
  RowMeta r;
  r.valid = validY && validX;
  r.ix = ix;
  if (r.valid){ r.relY = relY; r.relX = relX; r.spos = iy*128 + ix; }
  else { r.relY = (float)Y + 0.5f - 128.0f; r.relX = (float)X + 0.5f - 128.0f; r.spos = -1; }
  return r;
}

// --- kernel 0: weights -> bf16 N-major + U extra rows ------------------------
__global__ __launch_bounds__(256) void convert_weights(
    const float* __restrict__ W1, const float* __restrict__ b1,
    const float* __restrict__ W2, const float* __restrict__ W3,
    ushort* __restrict__ W1t,   // [256][384]
    ushort* __restrict__ W2t,   // [128][256]
    ushort* __restrict__ W3t,   // [32][128]
    ushort* __restrict__ Ub)    // rows 16384..16387 only
{
  int b = blockIdx.x, t = threadIdx.x;
  if (b < 384){
    int i = b*256 + t;
    { int k = i >> 8, n = i & 255; W1t[n*384 + k] = f2bf(W1[i]); }
    if (i < 32768){ int k = i >> 7, n = i & 127; W2t[n*256 + k] = f2bf(W2[i]); }
    if (i < 4096) { int k = i >> 5, n = i & 31;  W3t[n*128 + k] = f2bf(W3[i]); }
  } else {
    int r = b - 384;            // 0..3
    float v = (r == 0) ? W1[384*256 + t] : (r == 1) ? W1[385*256 + t]
            : (r == 2) ? b1[t] : 0.0f;
    Ub[(size_t)(16384 + r)*256 + t] = f2bf(v);
  }
}

// --- kernel 1: U GEMM. M-tile 32, N-half 128, grid 1024 (4 blocks/CU). ------
__global__ __launch_bounds__(256) void stage1_gemm(
    const float* __restrict__ src0, const float* __restrict__ src1,  // lr_guide, feat
    const ushort* __restrict__ W1t,
    ushort* __restrict__ outp)                 // [16384][256]
{
  __shared__ ushort A[32*136];
  const int t = threadIdx.x;
  const int w = t >> 6, lane = t & 63, quad = lane >> 4, l15 = lane & 15;
  const int pos0  = (blockIdx.x >> 1) * 32;
  const int nside = (blockIdx.x & 1) * 128;
  const int mt = w >> 1;               // 0..1
  const int ntb = (w & 1) * 4;         // n-tiles ntb..ntb+3 of this half

  f32x4 acc[4];
  #pragma unroll
  for (int nt=0; nt<4; nt++) acc[nt] = f32x4{0.f,0.f,0.f,0.f};

  for (int h=0; h<2; h++){
    const float* src = h ? src1 : src0;
    #pragma unroll
    for (int i=0; i<16; i++){
      int f = i*256 + t;
      int k = f >> 5, mm = f & 31;
      A[mm*136 + k] = f2bf(src[(size_t)k*16384 + pos0 + mm]);
    }
    __syncthreads();
    #pragma unroll
    for (int kt=0; kt<4; kt++){
      bf16x8 a = ld8(&A[(mt*16 + l15)*136 + kt*32 + quad*8]);
      #pragma unroll
      for (int nt=0; nt<4; nt++){
        bf16x8 b = ld8(&W1t[(size_t)(nside + (ntb+nt)*16 + l15)*384 + h*128 + kt*32 + quad*8]);
        acc[nt] = __builtin_amdgcn_mfma_f32_16x16x32_bf16(a, b, acc[nt], 0,0,0);
      }
    }
    __syncthreads();
  }
  #pragma unroll
  for (int nt=0; nt<4; nt++){
    int n = nside + (ntb+nt)*16 + l15;
    #pragma unroll
    for (int r=0; r<4; r++){
      int mm = mt*16 + quad*4 + r;
      outp[(size_t)(pos0 + mm)*256 + n] = f2bf(acc[nt][r]);
    }
  }
}

// --- kernel 2: fused main ----------------------------------------------------
__global__ __launch_bounds__(256, 4) void main_fused(
    const float* __restrict__ feat,      // [128][16384]
    const float* __restrict__ hr_guide,  // [128][65536]
    const float* __restrict__ b2v,
    const float* __restrict__ b3v,
    const ushort* __restrict__ Ub,       // [16388][256] bf16
    const ushort* __restrict__ W1t,      // [256][384] bf16 (N-major)
    const ushort* __restrict__ W2t,      // [128][256] bf16 (N-major)
    const ushort* __restrict__ W3t,      // [32][128]  bf16 (N-major)
    float* __restrict__ outp)            // [32][65536]
{
  __shared__ __align__(16) ushort A1[64*264];   // h1 (stride 264); h2 aliases (stride 136)
  __shared__ __align__(16) ushort Ahr[16*136];  // hr tile [pix][ch]
  __shared__ float gcs[64];
  __shared__ float wgt[64];

  const int t = threadIdx.x;
  const int w = t >> 6, lane = t & 63, quad = lane >> 4, l15 = lane & 15;
  const int Y  = blockIdx.x >> 4;
  const int X0 = (blockIdx.x & 15) << 4;
  const int iyA = (Y-1) >> 1, iyB = (Y+1) >> 1;
  const int ixbase = (X0-1) >> 1;

  // ---- phase 0: hr staging + gc dots ----
  #pragma unroll
  for (int i=0; i<2; i++){
    int id = i*256 + t;                 // 0..511
    int ch = id >> 2, xq = id & 3;
    float4 v = *(const float4*)(hr_guide + (size_t)ch*65536 + Y*256 + X0 + xq*4);
    Ahr[(xq*4+0)*136 + ch] = f2bf(v.x);
    Ahr[(xq*4+1)*136 + ch] = f2bf(v.y);
    Ahr[(xq*4+2)*136 + ch] = f2bf(v.z);
    Ahr[(xq*4+3)*136 + ch] = f2bf(v.w);
  }
  if (t < 64){
    RowMeta g = row_meta(Y, X0 + (t>>2), t & 3);
    float gc = 0.0f;
    if (g.spos >= 0){
      int bpos = (Y>>1)*128 + ((X0 + (t>>2)) >> 1);
      #pragma unroll
      for (int cc=0; cc<3; cc++)
        gc += feat[(size_t)(124+cc)*16384 + bpos] * feat[(size_t)(124+cc)*16384 + g.spos];
    }
    gcs[t] = gc;
  }
  __syncthreads();                                   // sync1
  if (t < 16){
    float g0 = gcs[t*4+0], g1 = gcs[t*4+1], g2 = gcs[t*4+2], g3 = gcs[t*4+3];
    float mx = fmaxf(fmaxf(g0,g1), fmaxf(g2,g3));
    float e0 = __expf(g0-mx), e1 = __expf(g1-mx), e2 = __expf(g2-mx), e3 = __expf(g3-mx);
    float inv = 1.0f/(e0+e1+e2+e3);
    wgt[t*4+0]=e0*inv; wgt[t*4+1]=e1*inv; wgt[t*4+2]=e2*inv; wgt[t*4+3]=e3*inv;
  }

  // ---- phase 1: h1^T = A(256xK) @ B(Kx64), K=160, relu -> A1 ----
  // A-row side table for kt=4 (k=128+s): s=0,1,2 -> Ub rows 16384..16386;
  // s=3..22 -> u-row (iy in {iyA,iyB}) x (ix = ixbase + u%10); s>=23 -> zero row.
  int uoff[8];                          // Ub element offsets, this thread's quad
  #pragma unroll
  for (int j=0; j<8; j++){
    int s = quad*8 + j;
    int u = s - 3;
    int iy = (u < 10) ? iyA : iyB;
    int ix = ixbase + (u - ((u < 10) ? 0 : 10));
    iy = min(max(iy, 0), 127); ix = min(max(ix, 0), 127);
    int rid = iy*128 + ix;
    rid = (s == 0) ? 16384 : (s == 1) ? 16385 : (s == 2) ? 16386
        : (s >= 23) ? 16387 : rid;
    uoff[j] = rid * 256;
  }
  // B kt=4 fragments per col-tile ct (cols = h1 rows 16ct..16ct+15)
  bf16x8 bk4[4];
  #pragma unroll
  for (int ct=0; ct<4; ct++){
    int m = 16*ct + l15;
    int pix = m >> 2, br = m & 3;
    RowMeta rm = row_meta(Y, X0 + pix, br);
    int sstar = rm.valid ? ((br >> 1)*10 + (rm.ix - ixbase) + 3) : -1;
    union { bf16x8 v; ushort s[8]; } bb;
    #pragma unroll
    for (int j=0; j<8; j++){
      int s = quad*8 + j;
      unsigned short val = 0;
      if (s == 0) val = f2bf(rm.relY);
      else if (s == 1) val = f2bf(rm.relX);
      else if (s == 2) val = 0x3F80u;
      if (s == sstar) val = 0x3F80u;
      bb.s[j] = val;
    }
    bk4[ct] = bb.v;
  }
  // main MFMA loop: wave w owns n = w*64 .. w*64+63 (4 n-tiles) x 4 col-tiles
  #pragma unroll
  for (int i=0; i<4; i++){
    int n = w*64 + i*16 + l15;
    const ushort* wp = W1t + (size_t)n*384 + 256;
    bf16x8 a0 = ld8(wp + 0*32 + quad*8);
    bf16x8 a1 = ld8(wp + 1*32 + quad*8);
    bf16x8 a2 = ld8(wp + 2*32 + quad*8);
    bf16x8 a3 = ld8(wp + 3*32 + quad*8);
    union { bf16x8 v; ushort s[8]; } a4;
    #pragma unroll
    for (int j=0; j<8; j++) a4.s[j] = Ub[(size_t)(uoff[j] + n)];
    #pragma unroll
    for (int ct=0; ct<4; ct++){
      const ushort* hp = &Ahr[(4*ct + (l15>>2))*136 + quad*8];
      f32x4 acc = f32x4{0.f,0.f,0.f,0.f};
      acc = __builtin_amdgcn_mfma_f32_16x16x32_bf16(a0, ld8(hp +  0), acc, 0,0,0);
      acc = __builtin_amdgcn_mfma_f32_16x16x32_bf16(a1, ld8(hp + 32), acc, 0,0,0);
      acc = __builtin_amdgcn_mfma_f32_16x16x32_bf16(a2, ld8(hp + 64), acc, 0,0,0);
      acc = __builtin_amdgcn_mfma_f32_16x16x32_bf16(a3, ld8(hp + 96), acc, 0,0,0);
      acc = __builtin_amdgcn_mfma_f32_16x16x32_bf16(a4.v, bk4[ct], acc, 0,0,0);
      // D: row(n) = quad*4+r, col(m) = l15 -> write relu(h1) 4 consecutive n
      int mrow = 16*ct + l15;
      int n0 = w*64 + i*16 + quad*4;
      uint2 o;
      o.x = (unsigned)f2bf(fmaxf(acc[0],0.f)) | ((unsigned)f2bf(fmaxf(acc[1],0.f)) << 16);
      o.y = (unsigned)f2bf(fmaxf(acc[2],0.f)) | ((unsigned)f2bf(fmaxf(acc[3],0.f)) << 16);
      *(uint2*)&A1[mrow*264 + n0] = o;
    }
  }
  __syncthreads();                                   // sync2

  // ---- phase 2: layer 2 [64x256] @ W2 [256x128]; wave owns 32 N-cols ----
  bf16x8 b2f[8][2];
  #pragma unroll
  for (int kt=0; kt<8; kt++)
    #pragma unroll
    for (int nt=0; nt<2; nt++)
      b2f[kt][nt] = ld8(&W2t[(size_t)(w*32 + nt*16 + l15)*256 + kt*32 + quad*8]);

  f32x4 acc2[4][2];
  #pragma unroll
  for (int mt=0; mt<4; mt++)
    #pragma unroll
    for (int nt=0; nt<2; nt++) acc2[mt][nt] = f32x4{0.f,0.f,0.f,0.f};
  #pragma unroll
  for (int mt=0; mt<4; mt++)
    #pragma unroll
    for (int kt=0; kt<8; kt++){
      bf16x8 a = ld8(&A1[(mt*16 + l15)*264 + kt*32 + quad*8]);
      #pragma unroll
      for (int nt=0; nt<2; nt++)
        acc2[mt][nt] = __builtin_amdgcn_mfma_f32_16x16x32_bf16(a, b2f[kt][nt], acc2[mt][nt], 0,0,0);
    }
  __syncthreads();                                   // sync3 (A1 reads done)

  // ---- phase 3: h2 -> A1 alias (stride 136) ----
  {
    ushort* A2 = A1;
    float bias0 = b2v[w*32 + l15], bias1 = b2v[w*32 + 16 + l15];
    #pragma unroll
    for (int mt=0; mt<4; mt++)
      #pragma unroll
      for (int nt=0; nt<2; nt++){
        int n = w*32 + nt*16 + l15;
        float bv = nt ? bias1 : bias0;
        #pragma unroll
        for (int r=0; r<4; r++){
          int mm = mt*16 + quad*4 + r;
          A2[mm*136 + n] = f2bf(fmaxf(acc2[mt][nt][r] + bv, 0.0f));
        }
      }
  }
  __syncthreads();                                   // sync4

  // ---- phase 4: layer 3 [64x128] @ W3 [128x32] + weighted epilogue ----
  {
    bf16x8 b3f[4][2];
    #pragma unroll
    for (int kt=0; kt<4; kt++)
      #pragma unroll
      for (int nt=0; nt<2; nt++)
        b3f[kt][nt] = ld8(&W3t[(size_t)(nt*16 + l15)*128 + kt*32 + quad*8]);

    const ushort* A2 = A1;
    f32x4 acc3[2] = { f32x4{0.f,0.f,0.f,0.f}, f32x4{0.f,0.f,0.f,0.f} };
    #pragma unroll
    for (int kt=0; kt<4; kt++){
      bf16x8 a = ld8(&A2[(w*16 + l15)*136 + kt*32 + quad*8]);
      #pragma unroll
      for (int nt=0; nt<2; nt++)
        acc3[nt] = __builtin_amdgcn_mfma_f32_16x16x32_bf16(a, b3f[kt][nt], acc3[nt], 0,0,0);
    }
    int lp = w*4 + quad;                 // pixel; rows were m = w*16+quad*4+br
    int X = X0 + lp;
    float w0 = wgt[lp*4+0], w1 = wgt[lp*4+1], w2 = wgt[lp*4+2], w3 = wgt[lp*4+3];
    #pragma unroll
    for (int nt=0; nt<2; nt++){
      int n = nt*16 + l15;
      float bb = b3v[n];
      float v = w0*(acc3[nt][0]+bb) + w1*(acc3[nt][1]+bb)
              + w2*(acc3[nt][2]+bb) + w3*(acc3[nt][3]+bb);
      outp[(size_t)n*65536 + (size_t)Y*256 + X] = v;
    }
  }
}

extern "C" void kernel_launch(void* const* d_in, const int* in_sizes, int n_in,
                              void* d_out, int out_size, void* d_ws, size_t ws_size,
                              hipStream_t stream)
{
  const float* feat     = (const float*)d_in[0];
  const float* lr_guide = (const float*)d_in[1];
  const float* hr_guide = (const float*)d_in[2];
  const float* W1       = (const float*)d_in[3];
  const float* b1       = (const float*)d_in[4];
  const float* W2       = (const float*)d_in[5];
  const float* b2       = (const float*)d_in[6];
  const float* W3       = (const float*)d_in[7];
  const float* b3       = (const float*)d_in[8];
  float* outp = (float*)d_out;

  char* ws = (char*)d_ws;
  ushort* W1t = (ushort*)(ws);                         // 98304 el  = 196608 B
  ushort* W2t = (ushort*)(ws + 196608);                // 32768 el  = 65536 B
  ushort* W3t = (ushort*)(ws + 196608 + 65536);        // 4096 el   = 8192 B
  ushort* Ub  = (ushort*)(ws + 196608 + 65536 + 8192); // 16388*256 el = 8390656 B

  convert_weights<<<388, 256, 0, stream>>>(W1, b1, W2, W3, W1t, W2t, W3t, Ub);
  stage1_gemm<<<1024, 256, 0, stream>>>(lr_guide, feat, W1t, Ub);
  main_fused<<<4096, 256, 0, stream>>>(feat, hr_guide, b2, b3,
                                       Ub, W1t, W2t, W3t, outp);
}